// Round 10
// baseline (299.889 us; speedup 1.0000x reference)
//
#include <hip/hip_runtime.h>

// Propagation: E = softsign(V V^T / sqrt(D)); out0 = E @ state; out1 = E @ V
// B=4, N=4096, D=256, fp32 in/out.
//
// Round 10 = R9 with GEMM2's B-operand moved from LDS (vjt) to REGISTERS with
// one-iteration prefetch distance:
//  - Bf[2][8] (64 VGPRs): at top of iter k, issue 8 global b128 loads from VT
//    for iter k+1. Register loads stay in flight across __syncthreads (no
//    vmcnt(0) drain needed for VGPR-dest loads) -> full-iter latency cover.
//  - vjt LDS buffer + its DMA staging deleted: -64 b128 LDS reads and -32
//    DMA writes per CU-iter on the saturated LDS pipe (~77% busy in R9).
//  - vj now double-buffered (staged at top of iter, full-iter DMA window).
//  - Everything else R9: S^T GEMM1 (A=vj LDS, B=Vi regs), Esh dbuf b64
//    epilogue, 2 barriers/iter, grid 256 = b x 32it(128 rows) x 2 jh,
//    partials in ws + combine kernel.
//  - Risk: ~256 unified VGPRs (spill => FETCH/WRITE jump; declared failure).
//  - fallback: round-1 fused kernel if ws too small.

#define B_  4
#define N_  4096
#define D_  256

typedef __attribute__((ext_vector_type(8))) short short8;
typedef __attribute__((ext_vector_type(4))) float floatx4;

__device__ __forceinline__ unsigned short f2bf(float f) {
    unsigned int u = __float_as_uint(f);
    u += 0x7fff + ((u >> 16) & 1);   // RTNE
    return (unsigned short)(u >> 16);
}

__device__ __forceinline__ void gl_lds16(const void* g, void* l) {
    __builtin_amdgcn_global_load_lds(
        (const __attribute__((address_space(1))) unsigned int*)g,
        (__attribute__((address_space(3))) unsigned int*)l, 16, 0, 0);
}
__device__ __forceinline__ void gl_lds4(const void* g, void* l) {
    __builtin_amdgcn_global_load_lds(
        (const __attribute__((address_space(1))) unsigned int*)g,
        (__attribute__((address_space(3))) unsigned int*)l, 4, 0, 0);
}

// ---------------- pre-pass: fp32 -> bf16, plus transpose ----------------
__global__ __launch_bounds__(256)
void prepass_kernel(const float* __restrict__ val,
                    unsigned short* __restrict__ Vb,
                    unsigned short* __restrict__ VT) {
    __shared__ unsigned short tile[64][68];
    const int t   = threadIdx.x;
    const int blk = blockIdx.x;            // b*256 + it*4 + dt
    const int b   = blk >> 8;
    const int it  = (blk >> 2) & 63;
    const int dt  = blk & 3;
    const int i0  = it * 64, d0 = dt * 64;
    const float*    vb  = val + (size_t)b * N_ * D_;
    unsigned short* Vbb = Vb  + (size_t)b * N_ * D_;
    unsigned short* VTb = VT  + (size_t)b * D_ * N_;

    #pragma unroll
    for (int q = 0; q < 4; ++q) {
        int idx = t + 256 * q;
        int row = idx >> 4;
        int c4  = idx & 15;
        float4 v = *(const float4*)(vb + (size_t)(i0 + row) * D_ + d0 + c4 * 4);
        ushort4 h;
        h.x = f2bf(v.x); h.y = f2bf(v.y); h.z = f2bf(v.z); h.w = f2bf(v.w);
        *(ushort4*)(Vbb + (size_t)(i0 + row) * D_ + d0 + c4 * 4) = h;
        *(ushort4*)&tile[row][c4 * 4] = h;
    }
    __syncthreads();
    #pragma unroll
    for (int q = 0; q < 4; ++q) {
        int dr = (t >> 4) + q * 16;
        int i4 = t & 15;
        ushort4 h;
        h.x = tile[i4 * 4 + 0][dr];
        h.y = tile[i4 * 4 + 1][dr];
        h.z = tile[i4 * 4 + 2][dr];
        h.w = tile[i4 * 4 + 3][dr];
        *(ushort4*)(VTb + (size_t)(d0 + dr) * N_ + i0 + i4 * 4) = h;
    }
}

// ---------------- main fused kernel ----------------
// grid 256 = b(4) x it(32, 128-row tiles) x jh(2).  512 threads, 8 waves:
// group g = i-half (64 rows); wave w4: r0=(w4>>1)*32 (i), c0=(w4&1)*32 (j).
// LDS map (bytes), total 103936:
//   vj   : 0 + buf*32768        (2 x 32768)  [64 j][256 d] granule-swizzled
//   Esh  : 65536 + g*18432 + buf*9216        (2 g x 2 buf x 64 x 72 bf16)
//   stj  : 102400 + buf*256     (2 x 256)    64 f32
//   dsred: 102912 + g*512       (2 x 512)    [2][64] f32 per group
__global__ __launch_bounds__(512, 1)
void prop_main(const float* __restrict__ state,
               const unsigned short* __restrict__ Vb,
               const unsigned short* __restrict__ VT,
               float* __restrict__ dvp,   // [2][B][N][D] partials
               float* __restrict__ dsp_o) // [2][B][N]    partials
{
    __shared__ __attribute__((aligned(16))) unsigned char smem[103936];

    const int t    = threadIdx.x;
    const int g    = t >> 8;          // wave-group (i-half) 0/1
    const int w    = t >> 6;          // wave 0..7
    const int w4   = w & 3;           // wave within group
    const int lane = t & 63;
    const int quad = lane >> 4;
    const int l16  = lane & 15;

    const int x   = blockIdx.x;
    const int b   = x >> 6;
    const int it  = (x >> 1) & 31;
    const int jh  = x & 1;
    const int it0 = it * 128;
    const int jbase = jh * 2048;
    const int niter = 32;

    const unsigned short* Vbb = Vb + (size_t)b * N_ * D_;
    const unsigned short* VTb = VT + (size_t)b * D_ * N_;
    const float*          stb = state + (size_t)b * N_;

    const int hi  = lane >> 5;
    const int p32 = lane & 31;

    int vgoff[4];   // vj: rows 2*(w*4+n)+hi, granule-swizzled
    #pragma unroll
    for (int n = 0; n < 4; ++n) {
        int r  = 2 * (w * 4 + n) + hi;           // 0..63
        vgoff[n] = r * 256 + (p32 ^ (r & 7)) * 8;
    }

    const int r0 = (w4 >> 1) * 32;    // wave's i base within group
    const int c0 = (w4 & 1) * 32;     // wave's j base within tile
    const int pA = l16 & 7;

    // ---- Vi fragments in registers (64 VGPRs; GEMM1 B-operand) ----
    short8 A0[8], A1[8];
    {
        const unsigned short* ar0 = Vbb + (size_t)(it0 + g * 64 + r0 + l16) * 256 + quad * 8;
        const unsigned short* ar1 = ar0 + 16 * 256;
        #pragma unroll
        for (int ks = 0; ks < 8; ++ks) {
            A0[ks] = *(const short8*)(ar0 + ks * 32);
            A1[ks] = *(const short8*)(ar1 + ks * 32);
        }
    }

    // ---- GEMM2 B-operand global base: VT row d = w4*64 + c2*16 + l16 ----
    // element for (c2, ks): VTrow[jbase + k*64 + ks*32 + quad*8]
    const unsigned short* gB[4];
    #pragma unroll
    for (int c2 = 0; c2 < 4; ++c2)
        gB[c2] = VTb + (size_t)(w4 * 64 + c2 * 16 + l16) * 4096
                     + jbase + quad * 8;

    // ---- prologue: stage vj(0)->buf0 + stj(0); prefetch Bf[0] for k=0 ----
    #pragma unroll
    for (int n = 0; n < 4; ++n)
        gl_lds16(Vbb + (size_t)jbase * 256 + vgoff[n], smem + (w * 4 + n) * 1024);
    if (w == 0) gl_lds4(stb + jbase + lane, smem + 102400);

    short8 Bf[2][8];                  // [buf][ks*4+c2], 64 VGPRs
    #pragma unroll
    for (int ks = 0; ks < 2; ++ks)
        #pragma unroll
        for (int c2 = 0; c2 < 4; ++c2)
            Bf[0][ks * 4 + c2] = *(const short8*)(gB[c2] + ks * 32);

    floatx4 dv[4][4];                 // GEMM2 acc: [i-tile][d-tile]
    #pragma unroll
    for (int a = 0; a < 4; ++a)
        #pragma unroll
        for (int c = 0; c < 4; ++c)
            dv[a][c] = (floatx4){0.f, 0.f, 0.f, 0.f};
    float dsp[2] = {0.f, 0.f};        // [ic]: i = r0 + ic*16 + l16

    for (int k = 0; k < niter; ++k) {
        const int buf = k & 1;
        unsigned short* Eshg = (unsigned short*)(smem + 65536 + g * 18432 + buf * 9216);
        const unsigned short* vjL = (const unsigned short*)(smem + buf * 32768);
        const float* stjL = (const float*)(smem + 102400 + buf * 256);

        __syncthreads();   // B1: vj[buf](k) + stj[buf](k) DMA drained

        // ---- stage vj(k+1)->buf^1 (full-iter DMA window) + prefetch Bf ----
        if (k + 1 < niter) {
            const size_t j0n = jbase + (size_t)(k + 1) * 64;
            #pragma unroll
            for (int n = 0; n < 4; ++n)
                gl_lds16(Vbb + j0n * 256 + vgoff[n],
                         smem + (buf ^ 1) * 32768 + (w * 4 + n) * 1024);
            if (w == 0) gl_lds4(stb + j0n + lane, smem + 102400 + (buf ^ 1) * 256);
            const int joff = (k + 1) * 64;
            #pragma unroll
            for (int ks = 0; ks < 2; ++ks)
                #pragma unroll
                for (int c2 = 0; c2 < 4; ++c2)
                    Bf[buf ^ 1][ks * 4 + c2] =
                        *(const short8*)(gB[c2] + joff + ks * 32);
        }

        // ---- GEMM1 (S^T): sa[ja][ic] = Vj(c0+ja*16) . Vi(r0+ic*16)^T ----
        floatx4 sa[2][2];
        #pragma unroll
        for (int a = 0; a < 2; ++a)
            #pragma unroll
            for (int c = 0; c < 2; ++c)
                sa[a][c] = (floatx4){0.f, 0.f, 0.f, 0.f};

        #pragma unroll
        for (int ks = 0; ks < 8; ++ks) {
            const int p = ((ks * 4 + quad) ^ pA) * 8;
            short8 aj0 = *(const short8*)&vjL[(c0 + l16) * 256 + p];
            short8 aj1 = *(const short8*)&vjL[(c0 + 16 + l16) * 256 + p];
            sa[0][0] = __builtin_amdgcn_mfma_f32_16x16x32_bf16(aj0, A0[ks], sa[0][0], 0, 0, 0);
            sa[0][1] = __builtin_amdgcn_mfma_f32_16x16x32_bf16(aj0, A1[ks], sa[0][1], 0, 0, 0);
            sa[1][0] = __builtin_amdgcn_mfma_f32_16x16x32_bf16(aj1, A0[ks], sa[1][0], 0, 0, 0);
            sa[1][1] = __builtin_amdgcn_mfma_f32_16x16x32_bf16(aj1, A1[ks], sa[1][1], 0, 0, 0);
        }

        // ---- softsign epilogue: e = s/(16+|s|) -> Esh b64 writes + ds ----
        // lane holds E[i = r0+ic*16+l16][j = c0+ja*16+quad*4+r]
        float4 stq[2];
        stq[0] = *(const float4*)&stjL[c0 + quad * 4];
        stq[1] = *(const float4*)&stjL[c0 + 16 + quad * 4];
        #pragma unroll
        for (int ja = 0; ja < 2; ++ja) {
            #pragma unroll
            for (int ic = 0; ic < 2; ++ic) {
                float e0 = sa[ja][ic][0] * __builtin_amdgcn_rcpf(16.0f + fabsf(sa[ja][ic][0]));
                float e1 = sa[ja][ic][1] * __builtin_amdgcn_rcpf(16.0f + fabsf(sa[ja][ic][1]));
                float e2 = sa[ja][ic][2] * __builtin_amdgcn_rcpf(16.0f + fabsf(sa[ja][ic][2]));
                float e3 = sa[ja][ic][3] * __builtin_amdgcn_rcpf(16.0f + fabsf(sa[ja][ic][3]));
                dsp[ic] += e0 * stq[ja].x + e1 * stq[ja].y + e2 * stq[ja].z + e3 * stq[ja].w;
                uint2 pk;
                pk.x = (unsigned int)f2bf(e0) | ((unsigned int)f2bf(e1) << 16);
                pk.y = (unsigned int)f2bf(e2) | ((unsigned int)f2bf(e3) << 16);
                *(uint2*)&Eshg[(r0 + ic * 16 + l16) * 72 + c0 + ja * 16 + quad * 4] = pk;
            }
        }
        __syncthreads();   // B2: Esh[buf] visible

        // ---- GEMM2: dval += E . Vj (A from Esh[buf], B from registers) ----
        #pragma unroll
        for (int ks = 0; ks < 2; ++ks) {
            short8 af[4];
            #pragma unroll
            for (int a2 = 0; a2 < 4; ++a2)
                af[a2] = *(const short8*)&Eshg[(a2 * 16 + l16) * 72 + ks * 32 + quad * 8];
            #pragma unroll
            for (int a2 = 0; a2 < 4; ++a2)
                #pragma unroll
                for (int c2 = 0; c2 < 4; ++c2)
                    dv[a2][c2] = __builtin_amdgcn_mfma_f32_16x16x32_bf16(
                        af[a2], Bf[buf][ks * 4 + c2], dv[a2][c2], 0, 0, 0);
        }
        // next barrier is B1 of iter k+1
    }

    // ---- epilogue: partial delta_val ----
    float* dvo = dvp + (size_t)jh * B_ * N_ * D_ + (size_t)b * N_ * D_
                     + (size_t)(it0 + g * 64) * D_;
    #pragma unroll
    for (int a2 = 0; a2 < 4; ++a2)
        #pragma unroll
        for (int c2 = 0; c2 < 4; ++c2)
            #pragma unroll
            for (int r = 0; r < 4; ++r) {
                const int il = a2 * 16 + quad * 4 + r;
                const int d  = w4 * 64 + c2 * 16 + l16;
                dvo[(size_t)il * D_ + d] = dv[a2][c2][r];
            }

    // ---- epilogue: partial delta_state ----
    #pragma unroll
    for (int ic = 0; ic < 2; ++ic) {
        float v = dsp[ic];
        v += __shfl_xor(v, 16);
        v += __shfl_xor(v, 32);
        dsp[ic] = v;
    }
    float* dsredg = (float*)(smem + 102912 + g * 512);
    if (quad == 0) {
        #pragma unroll
        for (int ic = 0; ic < 2; ++ic)
            dsredg[(w4 & 1) * 64 + r0 + ic * 16 + l16] = dsp[ic];
    }
    __syncthreads();
    if (t < 128) {
        const int gg = t >> 6;
        const int i  = t & 63;
        const float* dsr = (const float*)(smem + 102912 + gg * 512);
        dsp_o[(size_t)jh * B_ * N_ + (size_t)b * N_ + it0 + gg * 64 + i]
            = dsr[i] + dsr[64 + i];
    }
}

// ---------------- combine: out = sum of the two j-half partials ----------------
__global__ __launch_bounds__(256)
void combine_kernel(const float4* __restrict__ dv0, const float4* __restrict__ dv1,
                    const float*  __restrict__ ds0, const float*  __restrict__ ds1,
                    float* __restrict__ out) {
    const int NDV4 = B_ * N_ * D_ / 4;   // 1048576
    const int NDS  = B_ * N_;            // 16384
    int x = blockIdx.x * 256 + threadIdx.x;
    if (x < NDV4) {
        float4 a = dv0[x], c = dv1[x];
        float4 r;
        r.x = a.x + c.x; r.y = a.y + c.y; r.z = a.z + c.z; r.w = a.w + c.w;
        ((float4*)(out + NDS))[x] = r;
    } else {
        int y = (x - NDV4) * 4;
        if (y < NDS) {
            float4 a = *(const float4*)(ds0 + y);
            float4 c = *(const float4*)(ds1 + y);
            float4 r;
            r.x = a.x + c.x; r.y = a.y + c.y; r.z = a.z + c.z; r.w = a.w + c.w;
            *(float4*)(out + y) = r;
        }
    }
}

// ---------------- fallback (round-1 kernel, used if ws too small) ----------------
__global__ __launch_bounds__(256, 1)
void prop_kernel_fb(const float* __restrict__ val,
                    const float* __restrict__ state,
                    float* __restrict__ out) {
    __shared__ __attribute__((aligned(16))) unsigned short vi[64][264];
    __shared__ __attribute__((aligned(16))) unsigned short vj[64][264];
    __shared__ __attribute__((aligned(16))) unsigned short vjt[2048][8];
    __shared__ __attribute__((aligned(16))) unsigned short Esh[64][72];
    __shared__ float stj[64];
    __shared__ float dsred[2][64];

    const int t    = threadIdx.x;
    const int w    = t >> 6;
    const int lane = t & 63;
    const int quad = lane >> 4;
    const int l16  = lane & 15;
    const int b   = blockIdx.x >> 6;
    const int it0 = (blockIdx.x & 63) << 6;
    const float* valb = val   + (size_t)b * N_ * D_;
    const float* stb  = state + (size_t)b * N_;

    #pragma unroll
    for (int n = 0; n < 16; ++n) {
        int idx = t + 256 * n;
        int row = idx >> 6;
        int c4  = idx & 63;
        float4 v = *(const float4*)(valb + (size_t)(it0 + row) * D_ + c4 * 4);
        ushort4 h;
        h.x = f2bf(v.x); h.y = f2bf(v.y); h.z = f2bf(v.z); h.w = f2bf(v.w);
        *(ushort4*)&vi[row][c4 * 4] = h;
    }

    const int r0 = (w >> 1) * 32;
    const int c0 = (w & 1) * 32;
    floatx4 dv[4][4];
    #pragma unroll
    for (int a = 0; a < 4; ++a)
        #pragma unroll
        for (int c = 0; c < 4; ++c)
            dv[a][c] = (floatx4){0.f, 0.f, 0.f, 0.f};
    float dsp[8];
    #pragma unroll
    for (int k = 0; k < 8; ++k) dsp[k] = 0.f;

    for (int jt = 0; jt < 64; ++jt) {
        const int j0 = jt * 64;
        #pragma unroll
        for (int n = 0; n < 16; ++n) {
            int idx = t + 256 * n;
            int row = idx >> 6;
            int c4  = idx & 63;
            float4 v = *(const float4*)(valb + (size_t)(j0 + row) * D_ + c4 * 4);
            ushort4 h;
            h.x = f2bf(v.x); h.y = f2bf(v.y); h.z = f2bf(v.z); h.w = f2bf(v.w);
            *(ushort4*)&vj[row][c4 * 4] = h;
        }
        if (t < 64) stj[t] = stb[j0 + t];
        __syncthreads();

        #pragma unroll
        for (int n = 0; n < 8; ++n) {
            const int d  = t;
            const int jb = n;
            short8 pk;
            #pragma unroll
            for (int jj = 0; jj < 8; ++jj) pk[jj] = (short)vj[jb * 8 + jj][d];
            *(short8*)&vjt[d * 8 + (jb ^ (d & 7))][0] = pk;
        }

        floatx4 sa[2][2];
        #pragma unroll
        for (int a = 0; a < 2; ++a)
            #pragma unroll
            for (int c = 0; c < 2; ++c)
                sa[a][c] = (floatx4){0.f, 0.f, 0.f, 0.f};
        #pragma unroll
        for (int ks = 0; ks < 8; ++ks) {
            const int d0 = ks * 32 + quad * 8;
            short8 a0 = *(const short8*)&vi[r0 + l16][d0];
            short8 a1 = *(const short8*)&vi[r0 + 16 + l16][d0];
            short8 b0 = *(const short8*)&vj[c0 + l16][d0];
            short8 b1 = *(const short8*)&vj[c0 + 16 + l16][d0];
            sa[0][0] = __builtin_amdgcn_mfma_f32_16x16x32_bf16(a0, b0, sa[0][0], 0, 0, 0);
            sa[0][1] = __builtin_amdgcn_mfma_f32_16x16x32_bf16(a0, b1, sa[0][1], 0, 0, 0);
            sa[1][0] = __builtin_amdgcn_mfma_f32_16x16x32_bf16(a1, b0, sa[1][0], 0, 0, 0);
            sa[1][1] = __builtin_amdgcn_mfma_f32_16x16x32_bf16(a1, b1, sa[1][1], 0, 0, 0);
        }

        float stc0 = stj[c0 + l16];
        float stc1 = stj[c0 + 16 + l16];
        #pragma unroll
        for (int a = 0; a < 2; ++a) {
            #pragma unroll
            for (int r = 0; r < 4; ++r) {
                const int il = r0 + a * 16 + quad * 4 + r;
                float s0 = sa[a][0][r] * 0.0625f;
                float s1 = sa[a][1][r] * 0.0625f;
                float e0 = s0 / (1.0f + fabsf(s0));
                float e1 = s1 / (1.0f + fabsf(s1));
                dsp[a * 4 + r] += e0 * stc0 + e1 * stc1;
                Esh[il][c0 + l16]      = f2bf(e0);
                Esh[il][c0 + 16 + l16] = f2bf(e1);
            }
        }
        __syncthreads();

        #pragma unroll
        for (int ks = 0; ks < 2; ++ks) {
            short8 af[4], bfr[4];
            #pragma unroll
            for (int a2 = 0; a2 < 4; ++a2)
                af[a2] = *(const short8*)&Esh[a2 * 16 + l16][ks * 32 + quad * 8];
            #pragma unroll
            for (int c2 = 0; c2 < 4; ++c2) {
                const int d  = w * 64 + c2 * 16 + l16;
                const int jb = ks * 4 + quad;
                bfr[c2] = *(const short8*)&vjt[d * 8 + (jb ^ (d & 7))][0];
            }
            #pragma unroll
            for (int a2 = 0; a2 < 4; ++a2)
                #pragma unroll
                for (int c2 = 0; c2 < 4; ++c2)
                    dv[a2][c2] = __builtin_amdgcn_mfma_f32_16x16x32_bf16(af[a2], bfr[c2], dv[a2][c2], 0, 0, 0);
        }
    }

    float* dvo = out + (size_t)B_ * N_ + (size_t)b * N_ * D_;
    #pragma unroll
    for (int a2 = 0; a2 < 4; ++a2)
        #pragma unroll
        for (int c2 = 0; c2 < 4; ++c2)
            #pragma unroll
            for (int r = 0; r < 4; ++r) {
                const int i = it0 + a2 * 16 + quad * 4 + r;
                const int d = w * 64 + c2 * 16 + l16;
                dvo[(size_t)i * D_ + d] = dv[a2][c2][r];
            }

    #pragma unroll
    for (int k = 0; k < 8; ++k) {
        float v = dsp[k];
        v += __shfl_xor(v, 1);
        v += __shfl_xor(v, 2);
        v += __shfl_xor(v, 4);
        v += __shfl_xor(v, 8);
        dsp[k] = v;
    }
    if (l16 == 0) {
        #pragma unroll
        for (int a = 0; a < 2; ++a)
            #pragma unroll
            for (int r = 0; r < 4; ++r) {
                const int row = (w >> 1) * 32 + a * 16 + quad * 4 + r;
                dsred[w & 1][row] = dsp[a * 4 + r];
            }
    }
    __syncthreads();
    if (t < 64) out[(size_t)b * N_ + it0 + t] = dsred[0][t] + dsred[1][t];
}

extern "C" void kernel_launch(void* const* d_in, const int* in_sizes, int n_in,
                              void* d_out, int out_size, void* d_ws, size_t ws_size,
                              hipStream_t stream) {
    const float* val   = (const float*)d_in[0];
    const float* state = (const float*)d_in[1];
    float* out = (float*)d_out;

    const size_t nE         = (size_t)B_ * N_ * D_;                 // 4,194,304
    const size_t need_base  = 2 * nE * sizeof(unsigned short);      // 16.78 MB
    const size_t need_split = need_base + 2 * nE * sizeof(float)
                            + 2 * (size_t)B_ * N_ * sizeof(float);  // ~50.5 MB

    if (ws_size >= need_split) {
        unsigned short* Vb = (unsigned short*)d_ws;
        unsigned short* VT = Vb + nE;
        float* dvp = (float*)(VT + nE);          // [2][B*N*D]
        float* dsp = dvp + 2 * nE;               // [2][B*N]
        prepass_kernel<<<dim3(1024), dim3(256), 0, stream>>>(val, Vb, VT);
        prop_main<<<dim3(256), dim3(512), 0, stream>>>(state, Vb, VT, dvp, dsp);
        const int NDV4 = B_ * N_ * D_ / 4;
        const int NDS4 = B_ * N_ / 4;
        combine_kernel<<<dim3((NDV4 + NDS4) / 256), dim3(256), 0, stream>>>(
            (const float4*)dvp, (const float4*)(dvp + nE),
            dsp, dsp + (size_t)B_ * N_, out);
    } else {
        prop_kernel_fb<<<dim3(256), dim3(256), 0, stream>>>(val, state, out);
    }
}

// Round 11
// 279.450 us; speedup vs baseline: 1.0731x; 1.0731x over previous
//
#include <hip/hip_runtime.h>

// Propagation: E = softsign(V V^T / sqrt(D)); out0 = E @ state; out1 = E @ V
// B=4, N=4096, D=256, fp32 in/out.
//
// Round 11 = R10 with the K-loop UNROLLED BY 2 so the double-buffer index is
// a compile-time literal everywhere. R10's 557 MB WRITE_SIZE was the compiler
// lowering the dynamically-indexed Bf[buf][..] register array to scratch;
// static indices let it live in VGPRs.
//  - GEMM2 B-operand in registers (Bf[2][8], prefetched one full iteration
//    ahead from VT; VGPR-dest loads stay in flight across __syncthreads).
//  - vjt LDS buffer + staging deleted; vj + stj double-buffered.
//  - S^T GEMM1 (A=vj LDS, B=Vi regs), Esh dbuf b64 epilogue, 2 barriers/iter.
//  - grid 256 = b x 32it(128 rows) x 2 jh; partials in ws + combine kernel.
//  - fallback: round-1 fused kernel if ws too small.

#define B_  4
#define N_  4096
#define D_  256

typedef __attribute__((ext_vector_type(8))) short short8;
typedef __attribute__((ext_vector_type(4))) float floatx4;

__device__ __forceinline__ unsigned short f2bf(float f) {
    unsigned int u = __float_as_uint(f);
    u += 0x7fff + ((u >> 16) & 1);   // RTNE
    return (unsigned short)(u >> 16);
}

__device__ __forceinline__ void gl_lds16(const void* g, void* l) {
    __builtin_amdgcn_global_load_lds(
        (const __attribute__((address_space(1))) unsigned int*)g,
        (__attribute__((address_space(3))) unsigned int*)l, 16, 0, 0);
}
__device__ __forceinline__ void gl_lds4(const void* g, void* l) {
    __builtin_amdgcn_global_load_lds(
        (const __attribute__((address_space(1))) unsigned int*)g,
        (__attribute__((address_space(3))) unsigned int*)l, 4, 0, 0);
}

// ---------------- pre-pass: fp32 -> bf16, plus transpose ----------------
__global__ __launch_bounds__(256)
void prepass_kernel(const float* __restrict__ val,
                    unsigned short* __restrict__ Vb,
                    unsigned short* __restrict__ VT) {
    __shared__ unsigned short tile[64][68];
    const int t   = threadIdx.x;
    const int blk = blockIdx.x;            // b*256 + it*4 + dt
    const int b   = blk >> 8;
    const int it  = (blk >> 2) & 63;
    const int dt  = blk & 3;
    const int i0  = it * 64, d0 = dt * 64;
    const float*    vb  = val + (size_t)b * N_ * D_;
    unsigned short* Vbb = Vb  + (size_t)b * N_ * D_;
    unsigned short* VTb = VT  + (size_t)b * D_ * N_;

    #pragma unroll
    for (int q = 0; q < 4; ++q) {
        int idx = t + 256 * q;
        int row = idx >> 4;
        int c4  = idx & 15;
        float4 v = *(const float4*)(vb + (size_t)(i0 + row) * D_ + d0 + c4 * 4);
        ushort4 h;
        h.x = f2bf(v.x); h.y = f2bf(v.y); h.z = f2bf(v.z); h.w = f2bf(v.w);
        *(ushort4*)(Vbb + (size_t)(i0 + row) * D_ + d0 + c4 * 4) = h;
        *(ushort4*)&tile[row][c4 * 4] = h;
    }
    __syncthreads();
    #pragma unroll
    for (int q = 0; q < 4; ++q) {
        int dr = (t >> 4) + q * 16;
        int i4 = t & 15;
        ushort4 h;
        h.x = tile[i4 * 4 + 0][dr];
        h.y = tile[i4 * 4 + 1][dr];
        h.z = tile[i4 * 4 + 2][dr];
        h.w = tile[i4 * 4 + 3][dr];
        *(ushort4*)(VTb + (size_t)(d0 + dr) * N_ + i0 + i4 * 4) = h;
    }
}

// ---------------- main fused kernel ----------------
// grid 256 = b(4) x it(32, 128-row tiles) x jh(2).  512 threads, 8 waves:
// group g = i-half (64 rows); wave w4: r0=(w4>>1)*32 (i), c0=(w4&1)*32 (j).
// LDS map (bytes), total 103936:
//   vj   : 0 + BUF*32768        (2 x 32768)  [64 j][256 d] granule-swizzled
//   Esh  : 65536 + g*18432 + BUF*9216        (2 g x 2 buf x 64 x 72 bf16)
//   stj  : 102400 + BUF*256     (2 x 256)    64 f32
//   dsred: 102912 + g*512       (2 x 512)    [2][64] f32 per group
__global__ __launch_bounds__(512, 1)
void prop_main(const float* __restrict__ state,
               const unsigned short* __restrict__ Vb,
               const unsigned short* __restrict__ VT,
               float* __restrict__ dvp,   // [2][B][N][D] partials
               float* __restrict__ dsp_o) // [2][B][N]    partials
{
    __shared__ __attribute__((aligned(16))) unsigned char smem[103936];

    const int t    = threadIdx.x;
    const int g    = t >> 8;          // wave-group (i-half) 0/1
    const int w    = t >> 6;          // wave 0..7
    const int w4   = w & 3;           // wave within group
    const int lane = t & 63;
    const int quad = lane >> 4;
    const int l16  = lane & 15;

    const int x   = blockIdx.x;
    const int b   = x >> 6;
    const int it  = (x >> 1) & 31;
    const int jh  = x & 1;
    const int it0 = it * 128;
    const int jbase = jh * 2048;
    const int niter = 32;

    const unsigned short* Vbb = Vb + (size_t)b * N_ * D_;
    const unsigned short* VTb = VT + (size_t)b * D_ * N_;
    const float*          stb = state + (size_t)b * N_;

    const int hi  = lane >> 5;
    const int p32 = lane & 31;

    int vgoff[4];   // vj: rows 2*(w*4+n)+hi, granule-swizzled
    #pragma unroll
    for (int n = 0; n < 4; ++n) {
        int r  = 2 * (w * 4 + n) + hi;           // 0..63
        vgoff[n] = r * 256 + (p32 ^ (r & 7)) * 8;
    }

    const int r0 = (w4 >> 1) * 32;    // wave's i base within group
    const int c0 = (w4 & 1) * 32;     // wave's j base within tile
    const int pA = l16 & 7;

    // ---- Vi fragments in registers (64 VGPRs; GEMM1 B-operand) ----
    short8 A0[8], A1[8];
    {
        const unsigned short* ar0 = Vbb + (size_t)(it0 + g * 64 + r0 + l16) * 256 + quad * 8;
        const unsigned short* ar1 = ar0 + 16 * 256;
        #pragma unroll
        for (int ks = 0; ks < 8; ++ks) {
            A0[ks] = *(const short8*)(ar0 + ks * 32);
            A1[ks] = *(const short8*)(ar1 + ks * 32);
        }
    }

    // ---- GEMM2 B-operand global base: VT row d = w4*64 + c2*16 + l16 ----
    const unsigned short* gB[4];
    #pragma unroll
    for (int c2 = 0; c2 < 4; ++c2)
        gB[c2] = VTb + (size_t)(w4 * 64 + c2 * 16 + l16) * 4096
                     + jbase + quad * 8;

    // ---- prologue: stage vj(0)->buf0 + stj(0); prefetch Bf[0] for k=0 ----
    #pragma unroll
    for (int n = 0; n < 4; ++n)
        gl_lds16(Vbb + (size_t)jbase * 256 + vgoff[n], smem + (w * 4 + n) * 1024);
    if (w == 0) gl_lds4(stb + jbase + lane, smem + 102400);

    short8 Bf[2][8];                  // [buf][ks*4+c2] -- STATIC indices only
    #pragma unroll
    for (int ks = 0; ks < 2; ++ks)
        #pragma unroll
        for (int c2 = 0; c2 < 4; ++c2)
            Bf[0][ks * 4 + c2] = *(const short8*)(gB[c2] + ks * 32);

    floatx4 dv[4][4];                 // GEMM2 acc: [i-tile][d-tile]
    #pragma unroll
    for (int a = 0; a < 4; ++a)
        #pragma unroll
        for (int c = 0; c < 4; ++c)
            dv[a][c] = (floatx4){0.f, 0.f, 0.f, 0.f};
    float dsp[2] = {0.f, 0.f};        // [ic]: i = r0 + ic*16 + l16

    // ===== K-loop, unrolled by 2 so the buffer index is a literal =====
#define SUB_ITER(KK, BUF, HAVE_NEXT)                                          \
    {                                                                         \
        unsigned short* Eshg =                                                \
            (unsigned short*)(smem + 65536 + g * 18432 + (BUF) * 9216);       \
        const unsigned short* vjL =                                           \
            (const unsigned short*)(smem + (BUF) * 32768);                    \
        const float* stjL = (const float*)(smem + 102400 + (BUF) * 256);      \
        __syncthreads(); /* B1: vj[BUF](KK) + stj[BUF](KK) DMA drained */     \
        if (HAVE_NEXT) {                                                      \
            const size_t j0n = jbase + (size_t)((KK) + 1) * 64;               \
            _Pragma("unroll")                                                 \
            for (int n = 0; n < 4; ++n)                                       \
                gl_lds16(Vbb + j0n * 256 + vgoff[n],                          \
                         smem + (1 - (BUF)) * 32768 + (w * 4 + n) * 1024);    \
            if (w == 0)                                                       \
                gl_lds4(stb + j0n + lane,                                     \
                        smem + 102400 + (1 - (BUF)) * 256);                   \
            const int joff = ((KK) + 1) * 64;                                 \
            _Pragma("unroll")                                                 \
            for (int ks = 0; ks < 2; ++ks) {                                  \
                _Pragma("unroll")                                             \
                for (int c2 = 0; c2 < 4; ++c2)                                \
                    Bf[1 - (BUF)][ks * 4 + c2] =                              \
                        *(const short8*)(gB[c2] + joff + ks * 32);            \
            }                                                                 \
        }                                                                     \
        floatx4 sa[2][2];                                                     \
        _Pragma("unroll")                                                     \
        for (int a = 0; a < 2; ++a) {                                         \
            _Pragma("unroll")                                                 \
            for (int c = 0; c < 2; ++c)                                       \
                sa[a][c] = (floatx4){0.f, 0.f, 0.f, 0.f};                     \
        }                                                                     \
        _Pragma("unroll")                                                     \
        for (int ks = 0; ks < 8; ++ks) {                                      \
            const int p = ((ks * 4 + quad) ^ pA) * 8;                         \
            short8 aj0 = *(const short8*)&vjL[(c0 + l16) * 256 + p];          \
            short8 aj1 = *(const short8*)&vjL[(c0 + 16 + l16) * 256 + p];     \
            sa[0][0] = __builtin_amdgcn_mfma_f32_16x16x32_bf16(aj0, A0[ks], sa[0][0], 0, 0, 0); \
            sa[0][1] = __builtin_amdgcn_mfma_f32_16x16x32_bf16(aj0, A1[ks], sa[0][1], 0, 0, 0); \
            sa[1][0] = __builtin_amdgcn_mfma_f32_16x16x32_bf16(aj1, A0[ks], sa[1][0], 0, 0, 0); \
            sa[1][1] = __builtin_amdgcn_mfma_f32_16x16x32_bf16(aj1, A1[ks], sa[1][1], 0, 0, 0); \
        }                                                                     \
        float4 stq0 = *(const float4*)&stjL[c0 + quad * 4];                   \
        float4 stq1 = *(const float4*)&stjL[c0 + 16 + quad * 4];              \
        _Pragma("unroll")                                                     \
        for (int ja = 0; ja < 2; ++ja) {                                      \
            const float4 stq = ja ? stq1 : stq0;                              \
            _Pragma("unroll")                                                 \
            for (int ic = 0; ic < 2; ++ic) {                                  \
                float e0 = sa[ja][ic][0] * __builtin_amdgcn_rcpf(16.0f + fabsf(sa[ja][ic][0])); \
                float e1 = sa[ja][ic][1] * __builtin_amdgcn_rcpf(16.0f + fabsf(sa[ja][ic][1])); \
                float e2 = sa[ja][ic][2] * __builtin_amdgcn_rcpf(16.0f + fabsf(sa[ja][ic][2])); \
                float e3 = sa[ja][ic][3] * __builtin_amdgcn_rcpf(16.0f + fabsf(sa[ja][ic][3])); \
                dsp[ic] += e0 * stq.x + e1 * stq.y + e2 * stq.z + e3 * stq.w; \
                uint2 pk;                                                     \
                pk.x = (unsigned int)f2bf(e0) | ((unsigned int)f2bf(e1) << 16); \
                pk.y = (unsigned int)f2bf(e2) | ((unsigned int)f2bf(e3) << 16); \
                *(uint2*)&Eshg[(r0 + ic * 16 + l16) * 72 + c0 + ja * 16 + quad * 4] = pk; \
            }                                                                 \
        }                                                                     \
        __syncthreads(); /* B2: Esh[BUF] visible */                           \
        _Pragma("unroll")                                                     \
        for (int ks = 0; ks < 2; ++ks) {                                      \
            short8 af[4];                                                     \
            _Pragma("unroll")                                                 \
            for (int a2 = 0; a2 < 4; ++a2)                                    \
                af[a2] = *(const short8*)&Eshg[(a2 * 16 + l16) * 72 + ks * 32 + quad * 8]; \
            _Pragma("unroll")                                                 \
            for (int a2 = 0; a2 < 4; ++a2) {                                  \
                _Pragma("unroll")                                             \
                for (int c2 = 0; c2 < 4; ++c2)                                \
                    dv[a2][c2] = __builtin_amdgcn_mfma_f32_16x16x32_bf16(     \
                        af[a2], Bf[(BUF)][ks * 4 + c2], dv[a2][c2], 0, 0, 0); \
            }                                                                 \
        }                                                                     \
    }

    for (int k = 0; k < niter; k += 2) {
        SUB_ITER(k,     0, 1)                 // k even <= 30 -> k+1 exists
        SUB_ITER(k + 1, 1, (k + 2 < niter))   // last sub-iter skips prefetch
    }
#undef SUB_ITER

    // ---- epilogue: partial delta_val ----
    float* dvo = dvp + (size_t)jh * B_ * N_ * D_ + (size_t)b * N_ * D_
                     + (size_t)(it0 + g * 64) * D_;
    #pragma unroll
    for (int a2 = 0; a2 < 4; ++a2)
        #pragma unroll
        for (int c2 = 0; c2 < 4; ++c2)
            #pragma unroll
            for (int r = 0; r < 4; ++r) {
                const int il = a2 * 16 + quad * 4 + r;
                const int d  = w4 * 64 + c2 * 16 + l16;
                dvo[(size_t)il * D_ + d] = dv[a2][c2][r];
            }

    // ---- epilogue: partial delta_state ----
    #pragma unroll
    for (int ic = 0; ic < 2; ++ic) {
        float v = dsp[ic];
        v += __shfl_xor(v, 16);
        v += __shfl_xor(v, 32);
        dsp[ic] = v;
    }
    float* dsredg = (float*)(smem + 102912 + g * 512);
    if (quad == 0) {
        #pragma unroll
        for (int ic = 0; ic < 2; ++ic)
            dsredg[(w4 & 1) * 64 + r0 + ic * 16 + l16] = dsp[ic];
    }
    __syncthreads();
    if (t < 128) {
        const int gg = t >> 6;
        const int i  = t & 63;
        const float* dsr = (const float*)(smem + 102912 + gg * 512);
        dsp_o[(size_t)jh * B_ * N_ + (size_t)b * N_ + it0 + gg * 64 + i]
            = dsr[i] + dsr[64 + i];
    }
}

// ---------------- combine: out = sum of the two j-half partials ----------------
__global__ __launch_bounds__(256)
void combine_kernel(const float4* __restrict__ dv0, const float4* __restrict__ dv1,
                    const float*  __restrict__ ds0, const float*  __restrict__ ds1,
                    float* __restrict__ out) {
    const int NDV4 = B_ * N_ * D_ / 4;   // 1048576
    const int NDS  = B_ * N_;            // 16384
    int x = blockIdx.x * 256 + threadIdx.x;
    if (x < NDV4) {
        float4 a = dv0[x], c = dv1[x];
        float4 r;
        r.x = a.x + c.x; r.y = a.y + c.y; r.z = a.z + c.z; r.w = a.w + c.w;
        ((float4*)(out + NDS))[x] = r;
    } else {
        int y = (x - NDV4) * 4;
        if (y < NDS) {
            float4 a = *(const float4*)(ds0 + y);
            float4 c = *(const float4*)(ds1 + y);
            float4 r;
            r.x = a.x + c.x; r.y = a.y + c.y; r.z = a.z + c.z; r.w = a.w + c.w;
            *(float4*)(out + y) = r;
        }
    }
}

// ---------------- fallback (round-1 kernel, used if ws too small) ----------------
__global__ __launch_bounds__(256, 1)
void prop_kernel_fb(const float* __restrict__ val,
                    const float* __restrict__ state,
                    float* __restrict__ out) {
    __shared__ __attribute__((aligned(16))) unsigned short vi[64][264];
    __shared__ __attribute__((aligned(16))) unsigned short vj[64][264];
    __shared__ __attribute__((aligned(16))) unsigned short vjt[2048][8];
    __shared__ __attribute__((aligned(16))) unsigned short Esh[64][72];
    __shared__ float stj[64];
    __shared__ float dsred[2][64];

    const int t    = threadIdx.x;
    const int w    = t >> 6;
    const int lane = t & 63;
    const int quad = lane >> 4;
    const int l16  = lane & 15;
    const int b   = blockIdx.x >> 6;
    const int it0 = (blockIdx.x & 63) << 6;
    const float* valb = val   + (size_t)b * N_ * D_;
    const float* stb  = state + (size_t)b * N_;

    #pragma unroll
    for (int n = 0; n < 16; ++n) {
        int idx = t + 256 * n;
        int row = idx >> 6;
        int c4  = idx & 63;
        float4 v = *(const float4*)(valb + (size_t)(it0 + row) * D_ + c4 * 4);
        ushort4 h;
        h.x = f2bf(v.x); h.y = f2bf(v.y); h.z = f2bf(v.z); h.w = f2bf(v.w);
        *(ushort4*)&vi[row][c4 * 4] = h;
    }

    const int r0 = (w >> 1) * 32;
    const int c0 = (w & 1) * 32;
    floatx4 dv[4][4];
    #pragma unroll
    for (int a = 0; a < 4; ++a)
        #pragma unroll
        for (int c = 0; c < 4; ++c)
            dv[a][c] = (floatx4){0.f, 0.f, 0.f, 0.f};
    float dsp[8];
    #pragma unroll
    for (int k = 0; k < 8; ++k) dsp[k] = 0.f;

    for (int jt = 0; jt < 64; ++jt) {
        const int j0 = jt * 64;
        #pragma unroll
        for (int n = 0; n < 16; ++n) {
            int idx = t + 256 * n;
            int row = idx >> 6;
            int c4  = idx & 63;
            float4 v = *(const float4*)(valb + (size_t)(j0 + row) * D_ + c4 * 4);
            ushort4 h;
            h.x = f2bf(v.x); h.y = f2bf(v.y); h.z = f2bf(v.z); h.w = f2bf(v.w);
            *(ushort4*)&vj[row][c4 * 4] = h;
        }
        if (t < 64) stj[t] = stb[j0 + t];
        __syncthreads();

        #pragma unroll
        for (int n = 0; n < 8; ++n) {
            const int d  = t;
            const int jb = n;
            short8 pk;
            #pragma unroll
            for (int jj = 0; jj < 8; ++jj) pk[jj] = (short)vj[jb * 8 + jj][d];
            *(short8*)&vjt[d * 8 + (jb ^ (d & 7))][0] = pk;
        }

        floatx4 sa[2][2];
        #pragma unroll
        for (int a = 0; a < 2; ++a)
            #pragma unroll
            for (int c = 0; c < 2; ++c)
                sa[a][c] = (floatx4){0.f, 0.f, 0.f, 0.f};
        #pragma unroll
        for (int ks = 0; ks < 8; ++ks) {
            const int d0 = ks * 32 + quad * 8;
            short8 a0 = *(const short8*)&vi[r0 + l16][d0];
            short8 a1 = *(const short8*)&vi[r0 + 16 + l16][d0];
            short8 b0 = *(const short8*)&vj[c0 + l16][d0];
            short8 b1 = *(const short8*)&vj[c0 + 16 + l16][d0];
            sa[0][0] = __builtin_amdgcn_mfma_f32_16x16x32_bf16(a0, b0, sa[0][0], 0, 0, 0);
            sa[0][1] = __builtin_amdgcn_mfma_f32_16x16x32_bf16(a0, b1, sa[0][1], 0, 0, 0);
            sa[1][0] = __builtin_amdgcn_mfma_f32_16x16x32_bf16(a1, b0, sa[1][0], 0, 0, 0);
            sa[1][1] = __builtin_amdgcn_mfma_f32_16x16x32_bf16(a1, b1, sa[1][1], 0, 0, 0);
        }

        float stc0 = stj[c0 + l16];
        float stc1 = stj[c0 + 16 + l16];
        #pragma unroll
        for (int a = 0; a < 2; ++a) {
            #pragma unroll
            for (int r = 0; r < 4; ++r) {
                const int il = r0 + a * 16 + quad * 4 + r;
                float s0 = sa[a][0][r] * 0.0625f;
                float s1 = sa[a][1][r] * 0.0625f;
                float e0 = s0 / (1.0f + fabsf(s0));
                float e1 = s1 / (1.0f + fabsf(s1));
                dsp[a * 4 + r] += e0 * stc0 + e1 * stc1;
                Esh[il][c0 + l16]      = f2bf(e0);
                Esh[il][c0 + 16 + l16] = f2bf(e1);
            }
        }
        __syncthreads();

        #pragma unroll
        for (int ks = 0; ks < 2; ++ks) {
            short8 af[4], bfr[4];
            #pragma unroll
            for (int a2 = 0; a2 < 4; ++a2)
                af[a2] = *(const short8*)&Esh[a2 * 16 + l16][ks * 32 + quad * 8];
            #pragma unroll
            for (int c2 = 0; c2 < 4; ++c2) {
                const int d  = w * 64 + c2 * 16 + l16;
                const int jb = ks * 4 + quad;
                bfr[c2] = *(const short8*)&vjt[d * 8 + (jb ^ (d & 7))][0];
            }
            #pragma unroll
            for (int a2 = 0; a2 < 4; ++a2)
                #pragma unroll
                for (int c2 = 0; c2 < 4; ++c2)
                    dv[a2][c2] = __builtin_amdgcn_mfma_f32_16x16x32_bf16(af[a2], bfr[c2], dv[a2][c2], 0, 0, 0);
        }
    }

    float* dvo = out + (size_t)B_ * N_ + (size_t)b * N_ * D_;
    #pragma unroll
    for (int a2 = 0; a2 < 4; ++a2)
        #pragma unroll
        for (int c2 = 0; c2 < 4; ++c2)
            #pragma unroll
            for (int r = 0; r < 4; ++r) {
                const int i = it0 + a2 * 16 + quad * 4 + r;
                const int d = w * 64 + c2 * 16 + l16;
                dvo[(size_t)i * D_ + d] = dv[a2][c2][r];
            }

    #pragma unroll
    for (int k = 0; k < 8; ++k) {
        float v = dsp[k];
        v += __shfl_xor(v, 1);
        v += __shfl_xor(v, 2);
        v += __shfl_xor(v, 4);
        v += __shfl_xor(v, 8);
        dsp[k] = v;
    }
    if (l16 == 0) {
        #pragma unroll
        for (int a = 0; a < 2; ++a)
            #pragma unroll
            for (int r = 0; r < 4; ++r) {
                const int row = (w >> 1) * 32 + a * 16 + quad * 4 + r;
                dsred[w & 1][row] = dsp[a * 4 + r];
            }
    }
    __syncthreads();
    if (t < 64) out[(size_t)b * N_ + it0 + t] = dsred[0][t] + dsred[1][t];
}

extern "C" void kernel_launch(void* const* d_in, const int* in_sizes, int n_in,
                              void* d_out, int out_size, void* d_ws, size_t ws_size,
                              hipStream_t stream) {
    const float* val   = (const float*)d_in[0];
    const float* state = (const float*)d_in[1];
    float* out = (float*)d_out;

    const size_t nE         = (size_t)B_ * N_ * D_;                 // 4,194,304
    const size_t need_base  = 2 * nE * sizeof(unsigned short);      // 16.78 MB
    const size_t need_split = need_base + 2 * nE * sizeof(float)
                            + 2 * (size_t)B_ * N_ * sizeof(float);  // ~50.5 MB

    if (ws_size >= need_split) {
        unsigned short* Vb = (unsigned short*)d_ws;
        unsigned short* VT = Vb + nE;
        float* dvp = (float*)(VT + nE);          // [2][B*N*D]
        float* dsp = dvp + 2 * nE;               // [2][B*N]
        prepass_kernel<<<dim3(1024), dim3(256), 0, stream>>>(val, Vb, VT);
        prop_main<<<dim3(256), dim3(512), 0, stream>>>(state, Vb, VT, dvp, dsp);
        const int NDV4 = B_ * N_ * D_ / 4;
        const int NDS4 = B_ * N_ / 4;
        combine_kernel<<<dim3((NDV4 + NDS4) / 256), dim3(256), 0, stream>>>(
            (const float4*)dvp, (const float4*)(dvp + nE),
            dsp, dsp + (size_t)B_ * N_, out);
    } else {
        prop_kernel_fb<<<dim3(256), dim3(256), 0, stream>>>(val, state, out);
    }
}